// Round 2
// baseline (135.740 us; speedup 1.0000x reference)
//
#include <hip/hip_runtime.h>
#include <hip/hip_bf16.h>

// Problem constants
#define NQ 8192            // B*S flattened tokens
#define DIM 64             // embed dim
#define SPLITS 8           // key-dimension split (partials merged later)
#define QBLK 128           // queries per block (4 waves x 32)
#define BN 64              // keys per LDS tile
#define KEYS_PER_SPLIT (NQ / SPLITS)   // 1024
#define NTILES (KEYS_PER_SPLIT / BN)   // 16
#define SCALE 0.35355339059327373f     // 1/sqrt(8)

#define KSTR 72            // ksh row stride in shorts
#define PSTR 72            // psh row stride in shorts

typedef short s8v __attribute__((ext_vector_type(8)));   // 8 x bf16 bits (4 VGPRs)
typedef float f4v __attribute__((ext_vector_type(4)));

__device__ __forceinline__ float b2f(short s) {
  unsigned int u = ((unsigned int)(unsigned short)s) << 16;
  return __uint_as_float(u);
}
__device__ __forceinline__ short f2b(float f) {
  __hip_bfloat16 h = __float2bfloat16(f);
  return *reinterpret_cast<short*>(&h);
}

// ---------------- QKV projection + quantum map (fp32 in, bf16 out) ----------
// q_q[n,e] = cos(theta[e]) * cos( sum_d x[n,d]*W[e,d] + b[e] )
#define QROWS 16
__global__ __launch_bounds__(256) void qkv_kernel(
    const float* __restrict__ x,
    const float* __restrict__ wq, const float* __restrict__ bq,
    const float* __restrict__ wk, const float* __restrict__ bk,
    const float* __restrict__ wv, const float* __restrict__ bv,
    const float* __restrict__ theta,
    short* __restrict__ qq, short* __restrict__ kq, short* __restrict__ vq) {
  __shared__ float wsh[3][DIM][DIM + 1];   // padded: bank = (e+d)%32, 2-way free
  __shared__ float xs[QROWS][DIM];
  int tid = threadIdx.x;
  // stage the 3 weight matrices (48 KB) once per block
  for (int i = tid; i < 3 * DIM * (DIM / 4); i += 256) {
    int m = i / (DIM * DIM / 4);
    int rem = i % (DIM * DIM / 4);
    int r = rem / (DIM / 4);
    int c4 = (rem % (DIM / 4)) * 4;
    const float* src = (m == 0) ? wq : (m == 1) ? wk : wv;
    float4 v = *(const float4*)&src[r * DIM + c4];
    wsh[m][r][c4 + 0] = v.x; wsh[m][r][c4 + 1] = v.y;
    wsh[m][r][c4 + 2] = v.z; wsh[m][r][c4 + 3] = v.w;
  }
  int rowbase = blockIdx.x * QROWS;
  for (int i = tid; i < QROWS * (DIM / 4); i += 256) {
    int r = i / (DIM / 4), c4 = (i % (DIM / 4)) * 4;
    float4 v = *(const float4*)&x[(rowbase + r) * DIM + c4];
    xs[r][c4 + 0] = v.x; xs[r][c4 + 1] = v.y;
    xs[r][c4 + 2] = v.z; xs[r][c4 + 3] = v.w;
  }
  __syncthreads();
  int e = tid & 63, rg = tid >> 6;
  float ct = __cosf(theta[e]);
  float bqv = bq[e], bkv = bk[e], bvv = bv[e];
  for (int r = rg; r < QROWS; r += 4) {
    float aq = bqv, ak = bkv, av = bvv;
#pragma unroll
    for (int d = 0; d < DIM; ++d) {
      float xv = xs[r][d];
      aq += xv * wsh[0][e][d];
      ak += xv * wsh[1][e][d];
      av += xv * wsh[2][e][d];
    }
    int n = rowbase + r;
    qq[n * DIM + e] = f2b(ct * __cosf(aq));
    kq[n * DIM + e] = f2b(ct * __cosf(ak));
    vq[n * DIM + e] = f2b(ct * __cosf(av));
  }
}

// ---------------- Flash attention (no-max streaming softmax) ----------------
// scores bounded: |s| <= 64/sqrt(8) = 22.6 -> exp(s) <= 6.6e9, sums <= 5.5e13,
// all safe in fp32 => skip running-max; partials merge by pure summation.
__global__ __launch_bounds__(256, 2) void flash_kernel(
    const short* __restrict__ qq, const short* __restrict__ kq,
    const short* __restrict__ vq,
    float* __restrict__ pO, float* __restrict__ pL) {
  __shared__ __align__(16) short ksh[BN * KSTR];      // [key][dim], stride 72
  __shared__ __align__(16) short vsh[DIM * BN];       // [dim][key], XOR-swizzled 16B blocks
  __shared__ __align__(16) short psh[4][32 * PSTR];   // per-wave P (32 q rows x 64 keys)

  int tid = threadIdx.x;
  int wave = tid >> 6, lane = tid & 63;
  int l15 = lane & 15, quad = lane >> 4;
  int qblock = blockIdx.x >> 3, split = blockIdx.x & 7;
  int qbase = qblock * QBLK + wave * 32;

  // Q fragments: A-layout  A[m=lane&15][k=quad*8+j], two k-steps of 32
  s8v qf[2][2];
#pragma unroll
  for (int qt = 0; qt < 2; ++qt) {
    const short* qr = qq + (qbase + qt * 16 + l15) * DIM + quad * 8;
    qf[qt][0] = *(const s8v*)qr;
    qf[qt][1] = *(const s8v*)(qr + 32);
  }

  f4v o[2][4];
  float ls[2][4];
#pragma unroll
  for (int qt = 0; qt < 2; ++qt)
#pragma unroll
    for (int c = 0; c < 4; ++c) {
      o[qt][c] = (f4v){0.f, 0.f, 0.f, 0.f};
      ls[qt][c] = 0.f;
    }

  int kstart = split * KEYS_PER_SPLIT;
  for (int t = 0; t < NTILES; ++t) {
    int kbase = kstart + t * BN;
    __syncthreads();  // (A) all waves done with previous tile's LDS
    // stage K: row-major, padded stride
    for (int i = tid; i < 512; i += 256) {
      int key = i >> 3, c8 = (i & 7) << 3;
      *(s8v*)&ksh[key * KSTR + c8] = *(const s8v*)&kq[(kbase + key) * DIM + c8];
    }
    // stage V transposed [dim][key], 16B key-blocks XOR-swizzled by dim
    for (int i = tid; i < 512; i += 256) {
      int key = i >> 3, d0 = (i & 7) << 3;
      s8v v = *(const s8v*)&vq[(kbase + key) * DIM + d0];
      int kb = key >> 3, ko = key & 7;
#pragma unroll
      for (int j = 0; j < 8; ++j) {
        int d = d0 + j;
        vsh[d * BN + (((kb ^ ((d ^ (d >> 3)) & 7)) << 3) + ko)] = v[j];
      }
    }
    __syncthreads();  // (B) staging visible

    // S = Q * K^T   (m=query, n=key, k=dim)
    f4v s[2][4];
#pragma unroll
    for (int n = 0; n < 4; ++n) {
      s8v kf0 = *(const s8v*)&ksh[(n * 16 + l15) * KSTR + quad * 8];
      s8v kf1 = *(const s8v*)&ksh[(n * 16 + l15) * KSTR + 32 + quad * 8];
#pragma unroll
      for (int qt = 0; qt < 2; ++qt) {
        f4v acc = {0.f, 0.f, 0.f, 0.f};
        acc = __builtin_amdgcn_mfma_f32_16x16x32_bf16(qf[qt][0], kf0, acc, 0, 0, 0);
        acc = __builtin_amdgcn_mfma_f32_16x16x32_bf16(qf[qt][1], kf1, acc, 0, 0, 0);
        s[qt][n] = acc;
      }
    }

    // P = exp(S*scale); accumulate row sums from the bf16-rounded P; write
    // P to per-wave LDS in C-layout (row=quad*4+r, col=n*16+l15)
#pragma unroll
    for (int qt = 0; qt < 2; ++qt)
#pragma unroll
      for (int n = 0; n < 4; ++n)
#pragma unroll
        for (int r = 0; r < 4; ++r) {
          float p = __expf(s[qt][n][r] * SCALE);
          short pb = f2b(p);
          ls[qt][r] += b2f(pb);
          psh[wave][(qt * 16 + quad * 4 + r) * PSTR + n * 16 + l15] = pb;
        }
    __syncthreads();  // (C) P writes drained before A-frag reads

    // O += P * V   (m=query, n=dim, k=key)
    s8v pf[2][2];
#pragma unroll
    for (int qt = 0; qt < 2; ++qt) {
      pf[qt][0] = *(const s8v*)&psh[wave][(qt * 16 + l15) * PSTR + quad * 8];
      pf[qt][1] = *(const s8v*)&psh[wave][(qt * 16 + l15) * PSTR + 32 + quad * 8];
    }
#pragma unroll
    for (int c = 0; c < 4; ++c) {
      int d = c * 16 + l15;
      int sw = (d ^ (d >> 3)) & 7;
      s8v vf0 = *(const s8v*)&vsh[d * BN + ((quad ^ sw) << 3)];
      s8v vf1 = *(const s8v*)&vsh[d * BN + (((4 + quad) ^ sw) << 3)];
#pragma unroll
      for (int qt = 0; qt < 2; ++qt) {
        o[qt][c] = __builtin_amdgcn_mfma_f32_16x16x32_bf16(pf[qt][0], vf0, o[qt][c], 0, 0, 0);
        o[qt][c] = __builtin_amdgcn_mfma_f32_16x16x32_bf16(pf[qt][1], vf1, o[qt][c], 0, 0, 0);
      }
    }
  }

  // row-sum reduce across the 16 lanes holding one row's columns
#pragma unroll
  for (int qt = 0; qt < 2; ++qt)
#pragma unroll
    for (int r = 0; r < 4; ++r) {
      float v = ls[qt][r];
      v += __shfl_xor(v, 1);
      v += __shfl_xor(v, 2);
      v += __shfl_xor(v, 4);
      v += __shfl_xor(v, 8);
      ls[qt][r] = v;
    }

  // store unnormalized partials (fp32) + row sums
#pragma unroll
  for (int qt = 0; qt < 2; ++qt)
#pragma unroll
    for (int r = 0; r < 4; ++r) {
      int q = qbase + qt * 16 + quad * 4 + r;
#pragma unroll
      for (int c = 0; c < 4; ++c)
        pO[((size_t)split * NQ + q) * DIM + c * 16 + l15] = o[qt][c][r];
      if (l15 == 0) pL[split * NQ + q] = ls[qt][r];
    }
}

// ---------------- merge partials + output projection (fp32) ----------------
#define MROWS 4
__global__ __launch_bounds__(256) void merge_kernel(
    const float* __restrict__ pO, const float* __restrict__ pL,
    const float* __restrict__ wo, const float* __restrict__ bo,
    float* __restrict__ out) {
  __shared__ float wsh[DIM][DIM + 1];
  __shared__ float att[MROWS][DIM];
  int tid = threadIdx.x;
  for (int i = tid; i < DIM * (DIM / 4); i += 256) {
    int r = i / (DIM / 4), c4 = (i % (DIM / 4)) * 4;
    float4 v = *(const float4*)&wo[r * DIM + c4];
    wsh[r][c4 + 0] = v.x; wsh[r][c4 + 1] = v.y;
    wsh[r][c4 + 2] = v.z; wsh[r][c4 + 3] = v.w;
  }
  int e = tid & 63, rg = tid >> 6;
  int q = blockIdx.x * MROWS + rg;
  float s = 0.f;
#pragma unroll
  for (int sp = 0; sp < SPLITS; ++sp) s += pO[((size_t)sp * NQ + q) * DIM + e];
  float l = 0.f;
#pragma unroll
  for (int sp = 0; sp < SPLITS; ++sp) l += pL[sp * NQ + q];
  att[rg][e] = s / l;
  __syncthreads();
  float acc = bo[e];
#pragma unroll
  for (int d = 0; d < DIM; ++d) acc += att[rg][d] * wsh[e][d];
  out[q * DIM + e] = acc;
}

extern "C" void kernel_launch(void* const* d_in, const int* in_sizes, int n_in,
                              void* d_out, int out_size, void* d_ws, size_t ws_size,
                              hipStream_t stream) {
  const float* x  = (const float*)d_in[0];
  const float* wq = (const float*)d_in[1];
  const float* bq = (const float*)d_in[2];
  const float* wk = (const float*)d_in[3];
  const float* bk = (const float*)d_in[4];
  const float* wv = (const float*)d_in[5];
  const float* bv = (const float*)d_in[6];
  const float* th = (const float*)d_in[7];
  const float* wo = (const float*)d_in[8];
  const float* bo = (const float*)d_in[9];

  char* ws = (char*)d_ws;
  short* qq = (short*)(ws);                         // 1 MB
  short* kq = (short*)(ws + (1u << 20));            // 1 MB
  short* vq = (short*)(ws + (2u << 20));            // 1 MB
  float* pO = (float*)(ws + (3u << 20));            // SPLITS*NQ*DIM*4 = 16 MB
  float* pL = (float*)(ws + (3u << 20) + (size_t)SPLITS * NQ * DIM * 4);  // 256 KB

  hipLaunchKernelGGL(qkv_kernel, dim3(NQ / QROWS), dim3(256), 0, stream,
                     x, wq, bq, wk, bk, wv, bv, th, qq, kq, vq);
  hipLaunchKernelGGL(flash_kernel, dim3((NQ / QBLK) * SPLITS), dim3(256), 0, stream,
                     qq, kq, vq, pO, pL);
  hipLaunchKernelGGL(merge_kernel, dim3(NQ / MROWS), dim3(256), 0, stream,
                     pO, pL, wo, bo, (float*)d_out);
}

// Round 3
// 134.181 us; speedup vs baseline: 1.0116x; 1.0116x over previous
//
#include <hip/hip_runtime.h>
#include <hip/hip_bf16.h>

// Problem constants
#define NQ 8192            // B*S flattened tokens
#define DIM 64             // embed dim
#define SPLITS 8           // key-dimension split (partials merged later)
#define QBLK 128           // queries per block (4 waves x 32)
#define BN 64              // keys per LDS tile
#define KEYS_PER_SPLIT (NQ / SPLITS)   // 1024
#define NTILES (KEYS_PER_SPLIT / BN)   // 16
#define SCALE 0.35355339059327373f     // 1/sqrt(8)
#define SC2   0.51012301920911057f     // SCALE * log2(e)

#define KSTR 72            // ksh/wsh row stride in shorts (bank-friendly)
#define VSTR 68            // vsh row stride in shorts

typedef short s8v __attribute__((ext_vector_type(8)));   // 8 x bf16 bits
typedef short s4v __attribute__((ext_vector_type(4)));   // 4 x bf16 bits
typedef float f4v __attribute__((ext_vector_type(4)));

__device__ __forceinline__ float b2f(short s) {
  unsigned int u = ((unsigned int)(unsigned short)s) << 16;
  return __uint_as_float(u);
}
__device__ __forceinline__ short f2b(float f) {
  __hip_bfloat16 h = __float2bfloat16(f);
  return *reinterpret_cast<short*>(&h);
}

__device__ __forceinline__ f4v mfma16(s4v a, s4v b, f4v c) {
#if __has_builtin(__builtin_amdgcn_mfma_f32_16x16x16bf16_1k)
  return __builtin_amdgcn_mfma_f32_16x16x16bf16_1k(a, b, c, 0, 0, 0);
#else
  f4v d;
  asm volatile("v_mfma_f32_16x16x16_bf16 %0, %1, %2, %3"
               : "=v"(d) : "v"(a), "v"(b), "v"(c));
  return d;
#endif
}

// ---------------- QKV projection + quantum map (fp32 in, bf16 out) ----------
// q_q[n,e] = cos(theta[e]) * cos( sum_d x[n,d]*W[e,d] + b[e] )
#define QROWS 16
__global__ __launch_bounds__(256) void qkv_kernel(
    const float* __restrict__ x,
    const float* __restrict__ wq, const float* __restrict__ bq,
    const float* __restrict__ wk, const float* __restrict__ bk,
    const float* __restrict__ wv, const float* __restrict__ bv,
    const float* __restrict__ theta,
    short* __restrict__ qq, short* __restrict__ kq, short* __restrict__ vq) {
  __shared__ __align__(16) short wsh[3][DIM][KSTR];  // bf16 weights
  __shared__ __align__(16) short xsb[QROWS][DIM];    // bf16 x rows
  int tid = threadIdx.x;
  // stage 3 weight matrices as bf16 (12 float4 loads + 12 b64 writes / thread)
  for (int i = tid; i < 3 * DIM * 16; i += 256) {
    int m = i >> 10;
    int rem = i & 1023;
    int r = rem >> 4, c4 = (rem & 15) << 2;
    const float* src = (m == 0) ? wq : (m == 1) ? wk : wv;
    float4 w = *(const float4*)&src[r * DIM + c4];
    s4v p = {f2b(w.x), f2b(w.y), f2b(w.z), f2b(w.w)};
    *(s4v*)&wsh[m][r][c4] = p;
  }
  int rowbase = blockIdx.x * QROWS;
  for (int i = tid; i < QROWS * 16; i += 256) {
    int r = i >> 4, c4 = (i & 15) << 2;
    float4 v = *(const float4*)&x[(rowbase + r) * DIM + c4];
    s4v p = {f2b(v.x), f2b(v.y), f2b(v.z), f2b(v.w)};
    *(s4v*)&xsb[r][c4] = p;
  }
  __syncthreads();
  int e = tid & 63, rg = tid >> 6;
  float ct = __cosf(theta[e]);
  float bqv = bq[e], bkv = bk[e], bvv = bv[e];
  for (int r = rg; r < QROWS; r += 4) {
    float aq = bqv, ak = bkv, av = bvv;
#pragma unroll
    for (int c8 = 0; c8 < 8; ++c8) {
      s8v xv = *(const s8v*)&xsb[r][c8 * 8];
      s8v w0 = *(const s8v*)&wsh[0][e][c8 * 8];
      s8v w1 = *(const s8v*)&wsh[1][e][c8 * 8];
      s8v w2 = *(const s8v*)&wsh[2][e][c8 * 8];
#pragma unroll
      for (int j = 0; j < 8; ++j) {
        float xf = b2f(xv[j]);
        aq += xf * b2f(w0[j]);
        ak += xf * b2f(w1[j]);
        av += xf * b2f(w2[j]);
      }
    }
    int n = rowbase + r;
    qq[n * DIM + e] = f2b(ct * __cosf(aq));
    kq[n * DIM + e] = f2b(ct * __cosf(ak));
    vq[n * DIM + e] = f2b(ct * __cosf(av));
  }
}

// ---------------- Flash attention (no-max streaming softmax) ----------------
// scores bounded: |s| <= 64/sqrt(8) = 22.6 -> exp(s) <= 6.6e9, sums <= 5.5e13,
// all safe in fp32 => skip running-max; partials merge by pure summation.
// QK^T computed as S^T (A=K, B=Q) so the exp'd C-tile IS the A-operand layout
// of mfma_16x16x16_bf16 (k=quad*4+j) -> P never round-trips through LDS.
__global__ __launch_bounds__(256) void flash_kernel(
    const short* __restrict__ qq, const short* __restrict__ kq,
    const short* __restrict__ vq,
    float* __restrict__ pO, float* __restrict__ pL) {
  __shared__ __align__(16) short ksh[BN * KSTR];   // [key][dim], stride 72
  __shared__ __align__(16) short vsh[DIM * VSTR];  // [dim][key], stride 68

  int tid = threadIdx.x;
  int wave = tid >> 6, lane = tid & 63;
  int l15 = lane & 15, quad = lane >> 4;
  int qblock = blockIdx.x >> 3, split = blockIdx.x & 7;
  int qbase = qblock * QBLK + wave * 32;

  // Q B-frags: B[n=query=l15][k=dim=quad*8+j], two k-halves
  s8v qf[2][2];
#pragma unroll
  for (int qt = 0; qt < 2; ++qt) {
    const short* qr = qq + (qbase + qt * 16 + l15) * DIM + quad * 8;
    qf[qt][0] = *(const s8v*)qr;
    qf[qt][1] = *(const s8v*)(qr + 32);
  }

  f4v o[2][4];
  float ls[2] = {0.f, 0.f};
#pragma unroll
  for (int qt = 0; qt < 2; ++qt)
#pragma unroll
    for (int c = 0; c < 4; ++c) o[qt][c] = (f4v){0.f, 0.f, 0.f, 0.f};

  int kp = tid & 31, dch = tid >> 5;   // V-transpose staging coords

  int kstart = split * KEYS_PER_SPLIT;
  for (int t = 0; t < NTILES; ++t) {
    int kbase = kstart + t * BN;
    __syncthreads();  // (A) previous tile's LDS fully consumed
    // stage K rows (b128 writes, stride-72 rows)
    for (int i = tid; i < 512; i += 256) {
      int key = i >> 3, c8 = (i & 7) << 3;
      *(s8v*)&ksh[key * KSTR + c8] = *(const s8v*)&kq[(kbase + key) * DIM + c8];
    }
    // stage V transposed [dim][key]: load 2 key rows, write packed key-pairs
    {
      s8v r0 = *(const s8v*)&vq[(kbase + 2 * kp) * DIM + (dch << 3)];
      s8v r1 = *(const s8v*)&vq[(kbase + 2 * kp + 1) * DIM + (dch << 3)];
#pragma unroll
      for (int j = 0; j < 8; ++j) {
        int d = (dch << 3) + j;
        int pk = (int)(unsigned short)r0[j] | ((int)(unsigned short)r1[j] << 16);
        *(int*)&vsh[d * VSTR + 2 * kp] = pk;
      }
    }
    __syncthreads();  // (B) staging visible

#pragma unroll
    for (int kt = 0; kt < 4; ++kt) {
      // K A-frag: A[m=key=l15][k=dim=quad*8+j]
      const short* kr = &ksh[(kt * 16 + l15) * KSTR + quad * 8];
      s8v kf0 = *(const s8v*)kr;
      s8v kf1 = *(const s8v*)(kr + 32);
      s4v pa[2];
#pragma unroll
      for (int qt = 0; qt < 2; ++qt) {
        f4v acc = (f4v){0.f, 0.f, 0.f, 0.f};
        acc = __builtin_amdgcn_mfma_f32_16x16x32_bf16(kf0, qf[qt][0], acc, 0, 0, 0);
        acc = __builtin_amdgcn_mfma_f32_16x16x32_bf16(kf1, qf[qt][1], acc, 0, 0, 0);
        // acc[r] = S^T[key=kt*16+quad*4+r][query=qt*16+l15]
        s4v a;
        float sum = 0.f;
#pragma unroll
        for (int r = 0; r < 4; ++r) {
          float p = exp2f(acc[r] * SC2);
          short pb = f2b(p);
          a[r] = pb;
          sum += b2f(pb);
        }
        pa[qt] = a;        // A[m=query=l15][k=key=quad*4+j]  (PV operand!)
        ls[qt] += sum;
      }
#pragma unroll
      for (int c = 0; c < 4; ++c) {
        // V B-frag: B[n=dim=l15][k=key=quad*4+j]
        s4v vf = *(const s4v*)&vsh[(c * 16 + l15) * VSTR + kt * 16 + quad * 4];
#pragma unroll
        for (int qt = 0; qt < 2; ++qt)
          o[qt][c] = mfma16(pa[qt], vf, o[qt][c]);
      }
    }
  }

  // ls[qt] holds per-(query=l15) partial over this lane's quad keys:
  // finish sum across quads (lane bits 4,5)
#pragma unroll
  for (int qt = 0; qt < 2; ++qt) {
    float v = ls[qt];
    v += __shfl_xor(v, 16);
    v += __shfl_xor(v, 32);
    ls[qt] = v;
  }

  // store unnormalized partials (fp32) + row sums
  // o C-layout: row(quad*4+r)=query_local, col(l15)=dim_local
#pragma unroll
  for (int qt = 0; qt < 2; ++qt) {
#pragma unroll
    for (int r = 0; r < 4; ++r) {
      int q = qbase + qt * 16 + quad * 4 + r;
#pragma unroll
      for (int c = 0; c < 4; ++c)
        pO[((size_t)split * NQ + q) * DIM + c * 16 + l15] = o[qt][c][r];
    }
    if (quad == 0) pL[split * NQ + qbase + qt * 16 + l15] = ls[qt];
  }
}

// ---------------- merge partials + output projection (fp32) ----------------
#define MROWS 8
__global__ __launch_bounds__(256) void merge_kernel(
    const float* __restrict__ pO, const float* __restrict__ pL,
    const float* __restrict__ wo, const float* __restrict__ bo,
    float* __restrict__ out) {
  __shared__ __align__(16) short wsh[DIM][KSTR];  // bf16 wo
  __shared__ __align__(16) float att[MROWS][DIM];
  int tid = threadIdx.x;
  for (int i = tid; i < DIM * 16; i += 256) {
    int r = i >> 4, c4 = (i & 15) << 2;
    float4 w = *(const float4*)&wo[r * DIM + c4];
    s4v p = {f2b(w.x), f2b(w.y), f2b(w.z), f2b(w.w)};
    *(s4v*)&wsh[r][c4] = p;
  }
  int e = tid & 63, rg = tid >> 6;
  int q0 = blockIdx.x * MROWS;
  for (int rr = rg; rr < MROWS; rr += 4) {
    int q = q0 + rr;
    float s = 0.f, l = 0.f;
#pragma unroll
    for (int sp = 0; sp < SPLITS; ++sp) {
      s += pO[((size_t)sp * NQ + q) * DIM + e];
      l += pL[sp * NQ + q];
    }
    att[rr][e] = s / l;
  }
  __syncthreads();
  for (int rr = rg; rr < MROWS; rr += 4) {
    float acc = bo[e];
#pragma unroll
    for (int c8 = 0; c8 < 8; ++c8) {
      s8v w = *(const s8v*)&wsh[e][c8 * 8];
      float4 a0 = *(const float4*)&att[rr][c8 * 8];
      float4 a1 = *(const float4*)&att[rr][c8 * 8 + 4];
      acc += a0.x * b2f(w[0]) + a0.y * b2f(w[1]) + a0.z * b2f(w[2]) + a0.w * b2f(w[3])
           + a1.x * b2f(w[4]) + a1.y * b2f(w[5]) + a1.z * b2f(w[6]) + a1.w * b2f(w[7]);
    }
    out[(q0 + rr) * DIM + e] = acc;
  }
}

extern "C" void kernel_launch(void* const* d_in, const int* in_sizes, int n_in,
                              void* d_out, int out_size, void* d_ws, size_t ws_size,
                              hipStream_t stream) {
  const float* x  = (const float*)d_in[0];
  const float* wq = (const float*)d_in[1];
  const float* bq = (const float*)d_in[2];
  const float* wk = (const float*)d_in[3];
  const float* bk = (const float*)d_in[4];
  const float* wv = (const float*)d_in[5];
  const float* bv = (const float*)d_in[6];
  const float* th = (const float*)d_in[7];
  const float* wo = (const float*)d_in[8];
  const float* bo = (const float*)d_in[9];

  char* ws = (char*)d_ws;
  short* qq = (short*)(ws);                         // 1 MB
  short* kq = (short*)(ws + (1u << 20));            // 1 MB
  short* vq = (short*)(ws + (2u << 20));            // 1 MB
  float* pO = (float*)(ws + (3u << 20));            // SPLITS*NQ*DIM*4 = 16 MB
  float* pL = (float*)(ws + (3u << 20) + (size_t)SPLITS * NQ * DIM * 4);  // 256 KB

  hipLaunchKernelGGL(qkv_kernel, dim3(NQ / QROWS), dim3(256), 0, stream,
                     x, wq, bq, wk, bk, wv, bv, th, qq, kq, vq);
  hipLaunchKernelGGL(flash_kernel, dim3((NQ / QBLK) * SPLITS), dim3(256), 0, stream,
                     qq, kq, vq, pO, pL);
  hipLaunchKernelGGL(merge_kernel, dim3(NQ / MROWS), dim3(256), 0, stream,
                     pO, pL, wo, bo, (float*)d_out);
}